// Round 2
// baseline (133.840 us; speedup 1.0000x reference)
//
#include <hip/hip_runtime.h>
#include <hip/hip_bf16.h>
#include <stdint.h>
#include <stddef.h>

// Attention B=256,H=32,S=16,D=64: softmax(QK^T/sqrt(8) + ones) with JAX
// threefry dropout p=0.3 (key 42), then @V.
// R2: latency-bound fix. 2 heads per wave (grid 1024): head1 Q/K loads issued
// before head0 compute, head1 V during head0 PV -> 2nd head's HBM latency
// hidden. __syncthreads removed (LDS is per-wave; same-wave lgkmcnt orders it).
// V/P staged in LDS as bf16 via hw v_cvt_pk (RNE == old bf16_rne): PV inner
// loop has zero cvt, P-frag is one ds_read_b128. Threefry (data-independent)
// hoisted under load latency.
// R3: compile fix — __hip_bfloat162 not trivially copyable; use memcpy bitmove.

typedef __attribute__((ext_vector_type(8))) short short8;
typedef __attribute__((ext_vector_type(4))) float f32x4;
typedef __attribute__((ext_vector_type(4))) unsigned int u32x4;

#define VST 68  // V tile row stride (shorts): 8B-aligned rows, reads conflict-free
#define PST 24  // P tile row stride (shorts): 16B-aligned b128 frag reads

__device__ __forceinline__ unsigned short bf16_rne(float f) {
  unsigned u = __builtin_bit_cast(unsigned, f);
  unsigned r = 0x7FFFu + ((u >> 16) & 1u);
  return (unsigned short)((u + r) >> 16);
}

// packed f32x2 -> bf16x2, RNE via v_cvt_pk_bf16_f32 (compiler-generated)
__device__ __forceinline__ unsigned pk2_bf16(float a, float b) {
  float2 t; t.x = a; t.y = b;
  __hip_bfloat162 h = __float22bfloat162_rn(t);
  unsigned r;
  __builtin_memcpy(&r, &h, 4);
  return r;
}

// JAX threefry2x32, key=(0,42), counter (0, idx); draw = x0^x1. Bit-exact vs
// jax.random.bernoulli(jax.random.key(42), ...) — verified R0 (absmax 0.031).
__device__ __forceinline__ unsigned threefry_bits(unsigned idx) {
  const unsigned k0 = 0u, k1 = 42u;
  const unsigned k2 = k0 ^ k1 ^ 0x1BD11BDAu;
  unsigned x0 = k0;
  unsigned x1 = idx + k1;
#define TF_ROUND(r) { x0 += x1; x1 = (x1 << (r)) | (x1 >> (32 - (r))); x1 ^= x0; }
  TF_ROUND(13) TF_ROUND(15) TF_ROUND(26) TF_ROUND(6)
  x0 += k1; x1 += k2 + 1u;
  TF_ROUND(17) TF_ROUND(29) TF_ROUND(16) TF_ROUND(24)
  x0 += k2; x1 += k0 + 2u;
  TF_ROUND(13) TF_ROUND(15) TF_ROUND(26) TF_ROUND(6)
  x0 += k0; x1 += k1 + 3u;
  TF_ROUND(17) TF_ROUND(29) TF_ROUND(16) TF_ROUND(24)
  x0 += k1; x1 += k2 + 4u;
  TF_ROUND(13) TF_ROUND(15) TF_ROUND(26) TF_ROUND(6)
  x0 += k2; x1 += k0 + 5u;
#undef TF_ROUND
  return x0 ^ x1;
}

__device__ __forceinline__ void drop_mask(int bh, int g, int c, float* m) {
#pragma unroll
  for (int t = 0; t < 4; t++) {
    unsigned idx = ((unsigned)bh << 8) + (unsigned)((4 * g + t) * 16 + c);
    unsigned bits = threefry_bits(idx);
    float u = __builtin_bit_cast(float, 0x3F800000u | (bits >> 9)) - 1.0f;
    m[t] = (u < 0.7f) ? (1.0f / 0.7f) : 0.0f;
  }
}

// 8 f32 -> hi/lo bf16 split via cvt_pk pairs (~3 ops/elem vs ~12 bitwise)
__device__ __forceinline__ void cvt_hilo_f4(float4 a, float4 b, short8& hi, short8& lo) {
  float x[8] = {a.x, a.y, a.z, a.w, b.x, b.y, b.z, b.w};
  u32x4 hw, lw;
#pragma unroll
  for (int i = 0; i < 4; i++) {
    float e0 = x[2 * i], e1 = x[2 * i + 1];
    unsigned hp = pk2_bf16(e0, e1);
    float h0 = __builtin_bit_cast(float, hp << 16);
    float h1 = __builtin_bit_cast(float, hp & 0xFFFF0000u);
    unsigned lp = pk2_bf16(e0 - h0, e1 - h1);
    hw[i] = hp; lw[i] = lp;
  }
  hi = __builtin_bit_cast(short8, hw);
  lo = __builtin_bit_cast(short8, lw);
}

__global__ __launch_bounds__(256) void attn_kernel(
    const float* __restrict__ q, const float* __restrict__ k,
    const float* __restrict__ v, float* __restrict__ out) {
  // per-wave, per-head-parity LDS buffers (no cross-wave sharing -> no barrier)
  __shared__ __align__(16) unsigned short vst[4][2][16 * VST];  // 17408 B
  __shared__ __align__(16) unsigned short pst[4][2][16 * PST];  //  6144 B

  const int lane = threadIdx.x & 63;
  const int w = threadIdx.x >> 6;
  const int wid = blockIdx.x * 4 + w;  // 0..4095
  const int c = lane & 15;             // A/B frag row; C-layout col
  const int g = lane >> 4;             // quad
  const int bh0 = wid, bh1 = wid + 4096;

  float4 qv[2][4], kv[2][4], vt[2][4];

  // ---- issue head0 loads ----
  const float4* qr0 = (const float4*)(q + (size_t)bh0 * 1024 + c * 64 + g * 8);
  const float4* kr0 = (const float4*)(k + (size_t)bh0 * 1024 + c * 64 + g * 8);
  qv[0][0] = qr0[0]; qv[0][1] = qr0[1]; qv[0][2] = qr0[8]; qv[0][3] = qr0[9];
  kv[0][0] = kr0[0]; kv[0][1] = kr0[1]; kv[0][2] = kr0[8]; kv[0][3] = kr0[9];
  const float4* vs0 = (const float4*)(v + (size_t)bh0 * 1024);
#pragma unroll
  for (int p2 = 0; p2 < 4; p2++) vt[0][p2] = vs0[p2 * 64 + lane];

  // ---- issue head1 Q/K loads (hidden under head0 compute) ----
  const float4* qr1 = (const float4*)(q + (size_t)bh1 * 1024 + c * 64 + g * 8);
  const float4* kr1 = (const float4*)(k + (size_t)bh1 * 1024 + c * 64 + g * 8);
  qv[1][0] = qr1[0]; qv[1][1] = qr1[1]; qv[1][2] = qr1[8]; qv[1][3] = qr1[9];
  kv[1][0] = kr1[0]; kv[1][1] = kr1[1]; kv[1][2] = kr1[8]; kv[1][3] = kr1[9];

  // ---- dropout masks: data-independent VALU, runs under load latency ----
  float m[2][4];
  drop_mask(bh0, g, c, m[0]);
  drop_mask(bh1, g, c, m[1]);

#pragma unroll
  for (int it = 0; it < 2; it++) {
    // ---- Q/K hi/lo bf16 split ----
    short8 qhi0, qlo0, qhi1, qlo1, khi0, klo0, khi1, klo1;
    cvt_hilo_f4(qv[it][0], qv[it][1], qhi0, qlo0);
    cvt_hilo_f4(qv[it][2], qv[it][3], qhi1, qlo1);
    cvt_hilo_f4(kv[it][0], kv[it][1], khi0, klo0);
    cvt_hilo_f4(kv[it][2], kv[it][3], khi1, klo1);

    // ---- scores = Q K^T: hi*hi + lo*hi + hi*lo ----
    f32x4 acc = {0.f, 0.f, 0.f, 0.f};
    acc = __builtin_amdgcn_mfma_f32_16x16x32_bf16(qhi0, khi0, acc, 0, 0, 0);
    acc = __builtin_amdgcn_mfma_f32_16x16x32_bf16(qhi1, khi1, acc, 0, 0, 0);
    acc = __builtin_amdgcn_mfma_f32_16x16x32_bf16(qlo0, khi0, acc, 0, 0, 0);
    acc = __builtin_amdgcn_mfma_f32_16x16x32_bf16(qlo1, khi1, acc, 0, 0, 0);
    acc = __builtin_amdgcn_mfma_f32_16x16x32_bf16(qhi0, klo0, acc, 0, 0, 0);
    acc = __builtin_amdgcn_mfma_f32_16x16x32_bf16(qhi1, klo1, acc, 0, 0, 0);

    // C layout: acc[t] = S[4g+t][c]; softmax across c (16-lane groups).
    // +ones mask cancels in softmax.
    const float SCALE = 0.35355339059327373f;
    float ad[4];
#pragma unroll
    for (int t = 0; t < 4; t++) {
      float sv = acc[t] * SCALE;
      float mx = sv;
#pragma unroll
      for (int msk = 1; msk < 16; msk <<= 1) mx = fmaxf(mx, __shfl_xor(mx, msk));
      float p = __expf(sv - mx);
      float sum = p;
#pragma unroll
      for (int msk = 1; msk < 16; msk <<= 1) sum += __shfl_xor(sum, msk);
      ad[t] = (p / sum) * m[it][t];
    }

    // ---- stage V as bf16 (cvt_pk at write; rows 2-4-way max on write,
    //      reads conflict-free). lane holds V[4p+g][4c..4c+3]. ----
    unsigned short* vw = &vst[w][it][0];
#pragma unroll
    for (int p2 = 0; p2 < 4; p2++) {
      float4 vv = vt[it][p2];
      unsigned w0 = pk2_bf16(vv.x, vv.y), w1 = pk2_bf16(vv.z, vv.w);
      int t = 4 * p2 + g;
      *(uint2*)(&vw[t * VST + 4 * c]) = make_uint2(w0, w1);
    }

    // issue head1 V loads now: land under head0 PV + stores + head1 cvt
    if (it == 0) {
      const float4* vs1 = (const float4*)(v + (size_t)bh1 * 1024);
#pragma unroll
      for (int p2 = 0; p2 < 4; p2++) vt[1][p2] = vs1[p2 * 64 + lane];
    }

    // ---- stage P as bf16 (row-major, stride 24) ----
    unsigned short* pw = &pst[w][it][0];
#pragma unroll
    for (int t = 0; t < 4; t++) pw[(4 * g + t) * PST + c] = bf16_rne(ad[t]);

    // ---- PV: P-frag = one b128 read, V-frag = bf16 scalars (no cvt) ----
    short8 pa = {0, 0, 0, 0, 0, 0, 0, 0};
    if (g < 2) pa = *(const short8*)(&pw[c * PST + g * 8]);

    f32x4 oacc[4];
#pragma unroll
    for (int nt = 0; nt < 4; nt++) {
      short8 vb = {0, 0, 0, 0, 0, 0, 0, 0};
      if (g < 2) {
#pragma unroll
        for (int j = 0; j < 8; j++)
          vb[j] = (short)vw[(g * 8 + j) * VST + nt * 16 + c];
      }
      f32x4 z = {0.f, 0.f, 0.f, 0.f};
      oacc[nt] = __builtin_amdgcn_mfma_f32_16x16x32_bf16(pa, vb, z, 0, 0, 0);
    }

    float* op = out + (size_t)(it == 0 ? bh0 : bh1) * 1024;
#pragma unroll
    for (int nt = 0; nt < 4; nt++)
#pragma unroll
      for (int t = 0; t < 4; t++)
        op[(4 * g + t) * 64 + nt * 16 + c] = oacc[nt][t];
  }
}

extern "C" void kernel_launch(void* const* d_in, const int* in_sizes, int n_in,
                              void* d_out, int out_size, void* d_ws, size_t ws_size,
                              hipStream_t stream) {
  const float* q = (const float*)d_in[0];
  const float* k = (const float*)d_in[1];
  const float* v = (const float*)d_in[2];
  float* out = (float*)d_out;
  attn_kernel<<<1024, 256, 0, stream>>>(q, k, v, out);
}

// Round 3
// 133.156 us; speedup vs baseline: 1.0051x; 1.0051x over previous
//
#include <hip/hip_runtime.h>
#include <hip/hip_bf16.h>
#include <stdint.h>
#include <stddef.h>

// Attention B=256,H=32,S=16,D=64: softmax(QK^T/sqrt(8) + ones) with JAX
// threefry dropout p=0.3 (key 42), then @V.
// R3: 2 heads/wave (grid 1024), per-wave LDS (no barriers), bf16 LDS staging,
// threefry hoisted under load latency. Measured < 40us/dispatch.
// R4: swapped QK^T (compute S^T = mfma(K,Q)) -> row softmax is 3 VALU + 2 shfl
// instead of 8 shfl per t (32 -> 4 shfl/head); P staged with one ds_write_b64;
// LDS single-buffered across heads (same-wave DS ops are in-order): 11.5 KB;
// __launch_bounds__(256,4) pins VGPR <= 128 so all 4 blocks/CU stay resident.

typedef __attribute__((ext_vector_type(8))) short short8;
typedef __attribute__((ext_vector_type(4))) float f32x4;
typedef __attribute__((ext_vector_type(4))) unsigned int u32x4;

#define VST 68  // V tile row stride (shorts): 8B-aligned rows, reads ~conflict-free
#define PST 24  // P tile row stride (shorts): 16B-aligned b128 frag reads

// packed f32x2 -> bf16x2, RNE via v_cvt_pk_bf16_f32 (compiler-generated)
__device__ __forceinline__ unsigned pk2_bf16(float a, float b) {
  float2 t; t.x = a; t.y = b;
  __hip_bfloat162 h = __float22bfloat162_rn(t);
  unsigned r;
  __builtin_memcpy(&r, &h, 4);
  return r;
}

// JAX threefry2x32, key=(0,42), counter (0, idx); draw = x0^x1. Bit-exact vs
// jax.random.bernoulli(jax.random.key(42), ...) — verified R0 (absmax 0.031).
__device__ __forceinline__ unsigned threefry_bits(unsigned idx) {
  const unsigned k0 = 0u, k1 = 42u;
  const unsigned k2 = k0 ^ k1 ^ 0x1BD11BDAu;
  unsigned x0 = k0;
  unsigned x1 = idx + k1;
#define TF_ROUND(r) { x0 += x1; x1 = (x1 << (r)) | (x1 >> (32 - (r))); x1 ^= x0; }
  TF_ROUND(13) TF_ROUND(15) TF_ROUND(26) TF_ROUND(6)
  x0 += k1; x1 += k2 + 1u;
  TF_ROUND(17) TF_ROUND(29) TF_ROUND(16) TF_ROUND(24)
  x0 += k2; x1 += k0 + 2u;
  TF_ROUND(13) TF_ROUND(15) TF_ROUND(26) TF_ROUND(6)
  x0 += k0; x1 += k1 + 3u;
  TF_ROUND(17) TF_ROUND(29) TF_ROUND(16) TF_ROUND(24)
  x0 += k1; x1 += k2 + 4u;
  TF_ROUND(13) TF_ROUND(15) TF_ROUND(26) TF_ROUND(6)
  x0 += k2; x1 += k0 + 5u;
#undef TF_ROUND
  return x0 ^ x1;
}

// mask for element idx = bh*256 + base + t, t=0..3 (value includes 1/0.7 scale)
__device__ __forceinline__ void drop_mask(int bh, int base, float* m) {
#pragma unroll
  for (int t = 0; t < 4; t++) {
    unsigned idx = ((unsigned)bh << 8) + (unsigned)(base + t);
    unsigned bits = threefry_bits(idx);
    float u = __builtin_bit_cast(float, 0x3F800000u | (bits >> 9)) - 1.0f;
    m[t] = (u < 0.7f) ? (1.0f / 0.7f) : 0.0f;
  }
}

// 8 f32 -> hi/lo bf16 split via cvt_pk pairs (~3 ops/elem vs ~12 bitwise)
__device__ __forceinline__ void cvt_hilo_f4(float4 a, float4 b, short8& hi, short8& lo) {
  float x[8] = {a.x, a.y, a.z, a.w, b.x, b.y, b.z, b.w};
  u32x4 hw, lw;
#pragma unroll
  for (int i = 0; i < 4; i++) {
    float e0 = x[2 * i], e1 = x[2 * i + 1];
    unsigned hp = pk2_bf16(e0, e1);
    float h0 = __builtin_bit_cast(float, hp << 16);
    float h1 = __builtin_bit_cast(float, hp & 0xFFFF0000u);
    unsigned lp = pk2_bf16(e0 - h0, e1 - h1);
    hw[i] = hp; lw[i] = lp;
  }
  hi = __builtin_bit_cast(short8, hw);
  lo = __builtin_bit_cast(short8, lw);
}

__global__ __launch_bounds__(256, 4) void attn_kernel(
    const float* __restrict__ q, const float* __restrict__ k,
    const float* __restrict__ v, float* __restrict__ out) {
  // per-wave LDS, single-buffered across the 2 heads (same-wave DS ops are
  // processed in order -> head1 writes can't pass head0 reads)
  __shared__ __align__(16) unsigned short vst[4][16 * VST];  // 8704 B
  __shared__ __align__(16) unsigned short pst[4][16 * PST];  // 3072 B

  const int lane = threadIdx.x & 63;
  const int w = threadIdx.x >> 6;
  const int wid = blockIdx.x * 4 + w;  // 0..4095
  const int c = lane & 15;             // frag row; with swapped QK^T: q-row
  const int g = lane >> 4;             // quad
  const int bh0 = wid, bh1 = wid + 4096;

  float4 qv[2][4], kv[2][4], vt[2][4];

  // ---- issue head0 loads ----
  const float4* qr0 = (const float4*)(q + (size_t)bh0 * 1024 + c * 64 + g * 8);
  const float4* kr0 = (const float4*)(k + (size_t)bh0 * 1024 + c * 64 + g * 8);
  qv[0][0] = qr0[0]; qv[0][1] = qr0[1]; qv[0][2] = qr0[8]; qv[0][3] = qr0[9];
  kv[0][0] = kr0[0]; kv[0][1] = kr0[1]; kv[0][2] = kr0[8]; kv[0][3] = kr0[9];
  const float4* vs0 = (const float4*)(v + (size_t)bh0 * 1024);
#pragma unroll
  for (int p2 = 0; p2 < 4; p2++) vt[0][p2] = vs0[p2 * 64 + lane];

  // ---- issue head1 Q/K loads (hidden under head0 compute) ----
  const float4* qr1 = (const float4*)(q + (size_t)bh1 * 1024 + c * 64 + g * 8);
  const float4* kr1 = (const float4*)(k + (size_t)bh1 * 1024 + c * 64 + g * 8);
  qv[1][0] = qr1[0]; qv[1][1] = qr1[1]; qv[1][2] = qr1[8]; qv[1][3] = qr1[9];
  kv[1][0] = kr1[0]; kv[1][1] = kr1[1]; kv[1][2] = kr1[8]; kv[1][3] = kr1[9];

  // ---- dropout masks: data-independent VALU, runs under load latency ----
  // swapped layout: lane(c,g) reg t holds element (row=c, col=4g+t)
  float m[2][4];
  drop_mask(bh0, (c << 4) + 4 * g, m[0]);
  drop_mask(bh1, (c << 4) + 4 * g, m[1]);

#pragma unroll
  for (int it = 0; it < 2; it++) {
    // ---- Q/K hi/lo bf16 split ----
    short8 qhi0, qlo0, qhi1, qlo1, khi0, klo0, khi1, klo1;
    cvt_hilo_f4(qv[it][0], qv[it][1], qhi0, qlo0);
    cvt_hilo_f4(qv[it][2], qv[it][3], qhi1, qlo1);
    cvt_hilo_f4(kv[it][0], kv[it][1], khi0, klo0);
    cvt_hilo_f4(kv[it][2], kv[it][3], khi1, klo1);

    // ---- S^T = K Q^T (swapped operands): hi*hi + lo*hi + hi*lo ----
    // acc[t] = S[c][4g+t] -> row c is spread over regs t and lane-quads g.
    f32x4 acc = {0.f, 0.f, 0.f, 0.f};
    acc = __builtin_amdgcn_mfma_f32_16x16x32_bf16(khi0, qhi0, acc, 0, 0, 0);
    acc = __builtin_amdgcn_mfma_f32_16x16x32_bf16(khi1, qhi1, acc, 0, 0, 0);
    acc = __builtin_amdgcn_mfma_f32_16x16x32_bf16(klo0, qhi0, acc, 0, 0, 0);
    acc = __builtin_amdgcn_mfma_f32_16x16x32_bf16(klo1, qhi1, acc, 0, 0, 0);
    acc = __builtin_amdgcn_mfma_f32_16x16x32_bf16(khi0, qlo0, acc, 0, 0, 0);
    acc = __builtin_amdgcn_mfma_f32_16x16x32_bf16(khi1, qlo1, acc, 0, 0, 0);

    // ---- row softmax: 3 VALU + 2 shfl for max, same for sum ----
    // +ones mask cancels in softmax.
    const float SCALE = 0.35355339059327373f;
    float sv[4];
#pragma unroll
    for (int t = 0; t < 4; t++) sv[t] = acc[t] * SCALE;
    float mx = fmaxf(fmaxf(sv[0], sv[1]), fmaxf(sv[2], sv[3]));
    mx = fmaxf(mx, __shfl_xor(mx, 16));
    mx = fmaxf(mx, __shfl_xor(mx, 32));
    float p0 = __expf(sv[0] - mx), p1 = __expf(sv[1] - mx);
    float p2v = __expf(sv[2] - mx), p3 = __expf(sv[3] - mx);
    float sum = (p0 + p1) + (p2v + p3);
    sum += __shfl_xor(sum, 16);
    sum += __shfl_xor(sum, 32);
    float rs = 1.0f / sum;
    float ad[4] = {p0 * rs * m[it][0], p1 * rs * m[it][1],
                   p2v * rs * m[it][2], p3 * rs * m[it][3]};

    // ---- stage V as bf16 (cvt_pk at write). lane holds V[4p+g][4c..4c+3] ----
    unsigned short* vw = &vst[w][0];
#pragma unroll
    for (int p2 = 0; p2 < 4; p2++) {
      float4 vv = vt[it][p2];
      unsigned w0 = pk2_bf16(vv.x, vv.y), w1 = pk2_bf16(vv.z, vv.w);
      int t = 4 * p2 + g;
      *(uint2*)(&vw[t * VST + 4 * c]) = make_uint2(w0, w1);
    }

    // issue head1 V loads now: land under head0 PV + stores + head1 cvt
    if (it == 0) {
      const float4* vs1 = (const float4*)(v + (size_t)bh1 * 1024);
#pragma unroll
      for (int p2 = 0; p2 < 4; p2++) vt[1][p2] = vs1[p2 * 64 + lane];
    }

    // ---- stage P as bf16: one 8B packed write (row c, cols 4g..4g+3) ----
    unsigned short* pw = &pst[w][0];
    {
      unsigned w0 = pk2_bf16(ad[0], ad[1]), w1 = pk2_bf16(ad[2], ad[3]);
      *(uint2*)(&pw[c * PST + 4 * g]) = make_uint2(w0, w1);
    }

    // ---- PV: P-frag = one b128 read, V-frag = bf16 scalars (no cvt) ----
    short8 pa = {0, 0, 0, 0, 0, 0, 0, 0};
    if (g < 2) pa = *(const short8*)(&pw[c * PST + g * 8]);

    f32x4 oacc[4];
#pragma unroll
    for (int nt = 0; nt < 4; nt++) {
      short8 vb = {0, 0, 0, 0, 0, 0, 0, 0};
      if (g < 2) {
#pragma unroll
        for (int j = 0; j < 8; j++)
          vb[j] = (short)vw[(g * 8 + j) * VST + nt * 16 + c];
      }
      f32x4 z = {0.f, 0.f, 0.f, 0.f};
      oacc[nt] = __builtin_amdgcn_mfma_f32_16x16x32_bf16(pa, vb, z, 0, 0, 0);
    }

    float* op = out + (size_t)(it == 0 ? bh0 : bh1) * 1024;
#pragma unroll
    for (int nt = 0; nt < 4; nt++)
#pragma unroll
      for (int t = 0; t < 4; t++)
        op[(4 * g + t) * 64 + nt * 16 + c] = oacc[nt][t];
  }
}

extern "C" void kernel_launch(void* const* d_in, const int* in_sizes, int n_in,
                              void* d_out, int out_size, void* d_ws, size_t ws_size,
                              hipStream_t stream) {
  const float* q = (const float*)d_in[0];
  const float* k = (const float*)d_in[1];
  const float* v = (const float*)d_in[2];
  float* out = (float*)d_out;
  attn_kernel<<<1024, 256, 0, stream>>>(q, k, v, out);
}